// Round 6
// baseline (284.247 us; speedup 1.0000x reference)
//
#include <hip/hip_runtime.h>
#include <hip/hip_bf16.h>
#include <math.h>

#define T_DIM 256
#define B_DIM 256
#define H_DIM 512
#define K_DIM 64
#define LN2F 0.69314718055994531f

typedef __attribute__((ext_vector_type(8))) short bfrag_t;  // 8 bf16 (4 VGPRs)
typedef __attribute__((ext_vector_type(4))) float f4_t;     // 4 fp32

// Pack 8 fp32 -> 8 bf16 (RNE) for an MFMA A/B fragment.
__device__ inline bfrag_t pack8(float4 a, float4 b) {
  union { bfrag_t v; __hip_bfloat162 h[4]; } u;
  u.h[0] = __float22bfloat162_rn(float2{a.x, a.y});
  u.h[1] = __float22bfloat162_rn(float2{a.z, a.w});
  u.h[2] = __float22bfloat162_rn(float2{b.x, b.y});
  u.h[3] = __float22bfloat162_rn(float2{b.z, b.w});
  return u.v;
}

// ---------------------------------------------------------------------------
// W pre-convert + out zeroing (unchanged, verified).
// ---------------------------------------------------------------------------
__global__ __launch_bounds__(256) void wconv(const float* __restrict__ W,
                                             short* __restrict__ Wb,
                                             float* __restrict__ out) {
  if (blockIdx.x == 0 && threadIdx.x == 0) *out = 0.f;
  const int i = (blockIdx.x * 256 + threadIdx.x) * 8;
  const float4 a = *(const float4*)(W + i);
  const float4 b = *(const float4*)(W + i + 4);
  *(bfrag_t*)(Wb + i) = pack8(a, b);
}

// ---------------------------------------------------------------------------
// Emission GEMM v10 (unchanged, verified): 64x64 tile, BK=64, 1-deep A
// prefetch, LDS pad-8 bf16 A-staging, streamed L2 B-frags, 4 blocks/CU,
// raw-score epilogue + fp32 gold gather, bf16 emP output.
// ---------------------------------------------------------------------------
__global__ __launch_bounds__(256, 4) void emis_gemm10(
    const float* __restrict__ hid,   // [T*B, H]
    const short* __restrict__ Wb,    // [K,H] bf16
    const float* __restrict__ bias,  // [K]
    const int*   __restrict__ tags,  // [T,B]
    short* __restrict__ emPb,        // [16,256,64,16] bf16 (permuted exp scores)
    float* __restrict__ goldRaw)     // [T,B] raw score at gold tag (fp32)
{
  __shared__ __hip_bfloat16 AsH[2][64 * 72];     // 2 x 9216 B
  float* Cs = (float*)&AsH[0][0];                // epilogue reuse

  const int tid  = threadIdx.x;
  const int wv   = tid >> 6;
  const int lane = tid & 63;
  const int l16  = lane & 15;
  const int quad = lane >> 4;
  const int m0   = blockIdx.x * 64;

  const short* wb = Wb + ((wv * 16 + l16) * H_DIM + quad * 8);

  const int sr = tid >> 2;
  const int sc = (tid & 3) << 4;
  const float* hrow = hid + (size_t)(m0 + sr) * H_DIM + sc;

  f4_t acc[4];
#pragma unroll
  for (int mt = 0; mt < 4; ++mt) acc[mt] = (f4_t){0.f, 0.f, 0.f, 0.f};

  float4 p0 = *(const float4*)(hrow + 0);
  float4 p1 = *(const float4*)(hrow + 4);
  float4 p2 = *(const float4*)(hrow + 8);
  float4 p3 = *(const float4*)(hrow + 12);
  bfrag_t bc0 = *(const bfrag_t*)(wb + 0);
  bfrag_t bc1 = *(const bfrag_t*)(wb + 32);
  *(bfrag_t*)(&AsH[0][sr * 72 + sc + 0]) = pack8(p0, p1);
  *(bfrag_t*)(&AsH[0][sr * 72 + sc + 8]) = pack8(p2, p3);
  __syncthreads();

#pragma unroll
  for (int it = 0; it < 8; ++it) {
    bfrag_t bn0, bn1;
    if (it < 7) {
      p0 = *(const float4*)(hrow + (it + 1) * 64 + 0);
      p1 = *(const float4*)(hrow + (it + 1) * 64 + 4);
      p2 = *(const float4*)(hrow + (it + 1) * 64 + 8);
      p3 = *(const float4*)(hrow + (it + 1) * 64 + 12);
      bn0 = *(const bfrag_t*)(wb + (it + 1) * 64);
      bn1 = *(const bfrag_t*)(wb + (it + 1) * 64 + 32);
    }
#pragma unroll
    for (int kc2 = 0; kc2 < 2; ++kc2) {
      const bfrag_t bf = kc2 ? bc1 : bc0;
#pragma unroll
      for (int mt = 0; mt < 4; ++mt) {
        const bfrag_t af =
            *(const bfrag_t*)(&AsH[it & 1][(mt * 16 + l16) * 72 + kc2 * 32 + quad * 8]);
        acc[mt] = __builtin_amdgcn_mfma_f32_16x16x32_bf16(af, bf, acc[mt], 0, 0, 0);
      }
    }
    if (it < 7) {
      *(bfrag_t*)(&AsH[(it + 1) & 1][sr * 72 + sc + 0]) = pack8(p0, p1);
      *(bfrag_t*)(&AsH[(it + 1) & 1][sr * 72 + sc + 8]) = pack8(p2, p3);
      bc0 = bn0; bc1 = bn1;
    }
    __syncthreads();
  }

  const float bn = bias[wv * 16 + l16];
#pragma unroll
  for (int mt = 0; mt < 4; ++mt)
#pragma unroll
    for (int r = 0; r < 4; ++r)
      Cs[(mt * 16 + quad * 4 + r) * 68 + wv * 16 + l16] = acc[mt][r] + bn;
  __syncthreads();

  const int t  = m0 >> 8;
  const int b0 = m0 & 255;
  if (tid < 64) {
    const int tg = tags[t * B_DIM + b0 + tid];
    goldRaw[t * B_DIM + b0 + tid] = Cs[tid * 68 + tg];
  }

  const int g0 = b0 >> 4;
  const int bl = tid & 15;
  const int qq = (tid >> 4) & 3;
  const int gl = tid >> 6;
#pragma unroll
  for (int i2 = 0; i2 < 2; ++i2) {
    float4 v0 = *(const float4*)(&Cs[(gl * 16 + bl) * 68 + (i2 * 2 + 0) * 16 + qq * 4]);
    float4 v1 = *(const float4*)(&Cs[(gl * 16 + bl) * 68 + (i2 * 2 + 1) * 16 + qq * 4]);
    v0.x = __expf(v0.x); v0.y = __expf(v0.y); v0.z = __expf(v0.z); v0.w = __expf(v0.w);
    v1.x = __expf(v1.x); v1.y = __expf(v1.y); v1.z = __expf(v1.z); v1.w = __expf(v1.w);
    const size_t off = ((((size_t)(g0 + gl) * 256 + t) * 64 + qq * 16 + bl) << 4) + i2 * 8;
    *(bfrag_t*)(emPb + off) = pack8(v0, v1);
  }
}

// ---------------------------------------------------------------------------
// CRF DP v11: TWO independent DP chains per wave (software-SMT). Grid 16->8
// blocks; each block handles 32 batch columns as chain0/chain1, interleaved
// step-by-step so the scheduler fills chain0's stalls (MFMA latency, vmcnt,
// shfl) with chain1's instructions — at 1 wave/SIMD this is the only latency
// hiding available. Registers held ~flat vs v10: ring 4-deep/chain (64 VGPR
// total, same), aE/eend shared across chains, snap moved to LDS (predicated
// write on the rare hit step). Per-column math bit-identical to v10.
// ---------------------------------------------------------------------------
__global__ __launch_bounds__(128, 1) void crf_dp11(
    const short* __restrict__ emPb,
    const float* __restrict__ goldRaw,
    const int* __restrict__ lens,
    const int* __restrict__ tags,
    const float* __restrict__ trans,
    const float* __restrict__ beginT,
    const float* __restrict__ endT,
    float* __restrict__ out)
{
  const int g    = blockIdx.x;   // 8 blocks x 32 batch cols
  const int tid  = threadIdx.x;
  const int wv   = tid >> 6;     // 0 = forward, 1 = backward
  const int lane = tid & 63;
  const int n    = lane & 15;
  const int q    = lane >> 4;
  const int b0   = g * 32 + n;
  const int b1   = b0 + 16;

  __shared__ float xs[2 * 64 * 16];     // x_127 per chain per fwd-lane (8 KB)
  __shared__ float snapL[2 * 64 * 16];  // snap per chain per fwd-lane (8 KB)
  __shared__ int   Lxs[2 * 64];
  __shared__ float s0d[2 * 16];
  __shared__ int   Ls0[2 * 16];
  __shared__ float gpart;

  const int len0 = lens[b0], cap0 = len0 - 1;
  const int len1 = lens[b1], cap1 = len1 - 1;
  const short* base0 = emPb + (((size_t)(2 * g)     * 256) * 64 + lane) * 16;
  const short* base1 = emPb + (((size_t)(2 * g + 1) * 256) * 64 + lane) * 16;
  float* snp0 = &snapL[(0 * 64 + lane) * 16];
  float* snp1 = &snapL[(1 * 64 + lane) * 16];

  float y0[16], y1[16];
  int Lint0 = 0, Lint1 = 0, Lsnap0 = 0, Lsnap1 = 0;
  bfrag_t xb0, xb1, zb0, zb1;                    // loop-carried B-frags (fwd)
  bfrag_t fA0,fA1,fB0,fB1,fC0,fC1,fD0,fD1;       // chain0 ring (4-deep)
  bfrag_t gA0,gA1,gB0,gB1,gC0,gC1,gD0,gD1;       // chain1 ring
  float g0 = 0.f;

#define LOADW(D0, D1, BASE, t) { \
    D0 = *(const bfrag_t*)((BASE) + (size_t)(t) * 1024 + 0); \
    D1 = *(const bfrag_t*)((BASE) + (size_t)(t) * 1024 + 8); }

#define CVT16(DST, S0, S1) { \
    union { bfrag_t v; __hip_bfloat162 h[4]; } _c0, _c1; \
    _c0.v = (S0); _c1.v = (S1); \
    float2 _f; \
    _f = __bfloat1622float2(_c0.h[0]); DST[0] = _f.x; DST[1] = _f.y; \
    _f = __bfloat1622float2(_c0.h[1]); DST[2] = _f.x; DST[3] = _f.y; \
    _f = __bfloat1622float2(_c0.h[2]); DST[4] = _f.x; DST[5] = _f.y; \
    _f = __bfloat1622float2(_c0.h[3]); DST[6] = _f.x; DST[7] = _f.y; \
    _f = __bfloat1622float2(_c1.h[0]); DST[8] = _f.x; DST[9] = _f.y; \
    _f = __bfloat1622float2(_c1.h[1]); DST[10] = _f.x; DST[11] = _f.y; \
    _f = __bfloat1622float2(_c1.h[2]); DST[12] = _f.x; DST[13] = _f.y; \
    _f = __bfloat1622float2(_c1.h[3]); DST[14] = _f.x; DST[15] = _f.y; }

#define RESCALE(Y, LINT) { \
    float _m0 = fmaxf(fmaxf(Y[0], Y[1]), fmaxf(Y[2], Y[3])); \
    float _m1 = fmaxf(fmaxf(Y[4], Y[5]), fmaxf(Y[6], Y[7])); \
    float _m2 = fmaxf(fmaxf(Y[8], Y[9]), fmaxf(Y[10], Y[11])); \
    float _m3 = fmaxf(fmaxf(Y[12], Y[13]), fmaxf(Y[14], Y[15])); \
    float _mx = fmaxf(fmaxf(_m0, _m1), fmaxf(_m2, _m3)); \
    _mx = fmaxf(_mx, __shfl_xor(_mx, 16)); \
    _mx = fmaxf(_mx, __shfl_xor(_mx, 32)); \
    int _e; (void)frexpf(_mx, &_e); \
    LINT += _e; \
    _Pragma("unroll") for (int _k = 0; _k < 16; ++_k) Y[_k] = ldexpf(Y[_k], -_e); }

#define BUILDBV(S, B0, B1) { \
    union { bfrag_t v; __hip_bfloat162 h[4]; } _u0, _u1; \
    _u0.h[0] = __float22bfloat162_rn(float2{S[0], S[1]}); \
    _u0.h[1] = __float22bfloat162_rn(float2{S[2], S[3]}); \
    _u0.h[2] = __float22bfloat162_rn(float2{S[4], S[5]}); \
    _u0.h[3] = __float22bfloat162_rn(float2{S[6], S[7]}); \
    _u1.h[0] = __float22bfloat162_rn(float2{S[8], S[9]}); \
    _u1.h[1] = __float22bfloat162_rn(float2{S[10], S[11]}); \
    _u1.h[2] = __float22bfloat162_rn(float2{S[12], S[13]}); \
    _u1.h[3] = __float22bfloat162_rn(float2{S[14], S[15]}); \
    B0 = _u0.v; B1 = _u1.v; }

#define SNAPW(SNP, Y) { \
    ((f4_t*)(SNP))[0] = (f4_t){Y[0], Y[1], Y[2], Y[3]}; \
    ((f4_t*)(SNP))[1] = (f4_t){Y[4], Y[5], Y[6], Y[7]}; \
    ((f4_t*)(SNP))[2] = (f4_t){Y[8], Y[9], Y[10], Y[11]}; \
    ((f4_t*)(SNP))[3] = (f4_t){Y[12], Y[13], Y[14], Y[15]}; }

  const f4_t zro = (f4_t){0.f, 0.f, 0.f, 0.f};

  if (wv == 0) {
    // ---- forward wave: 2 interleaved chains ----
    bfrag_t aE[8];
#pragma unroll
    for (int jt = 0; jt < 4; ++jt)
#pragma unroll
      for (int kt = 0; kt < 2; ++kt) {
        union { bfrag_t v; __hip_bfloat16 h[8]; } u;
#pragma unroll
        for (int r = 0; r < 8; ++r) {
          const int i = (2 * kt + (r >> 2)) * 16 + q * 4 + (r & 3);
          u.h[r] = __float2bfloat16(__expf(trans[(jt * 16 + n) * K_DIM + i]));
        }
        aE[jt * 2 + kt] = u.v;
      }

#define STEPF(T, Y, BB0, BB1, W0, W1, CAP, LINT, LSNAP, SNP, RSC) { \
    float _w[16]; \
    CVT16(_w, W0, W1); \
    f4_t _a0 = __builtin_amdgcn_mfma_f32_16x16x32_bf16(aE[0], BB0, zro, 0, 0, 0); \
    f4_t _a1 = __builtin_amdgcn_mfma_f32_16x16x32_bf16(aE[2], BB0, zro, 0, 0, 0); \
    f4_t _a2 = __builtin_amdgcn_mfma_f32_16x16x32_bf16(aE[4], BB0, zro, 0, 0, 0); \
    f4_t _a3 = __builtin_amdgcn_mfma_f32_16x16x32_bf16(aE[6], BB0, zro, 0, 0, 0); \
    _a0 = __builtin_amdgcn_mfma_f32_16x16x32_bf16(aE[1], BB1, _a0, 0, 0, 0); \
    _a1 = __builtin_amdgcn_mfma_f32_16x16x32_bf16(aE[3], BB1, _a1, 0, 0, 0); \
    _a2 = __builtin_amdgcn_mfma_f32_16x16x32_bf16(aE[5], BB1, _a2, 0, 0, 0); \
    _a3 = __builtin_amdgcn_mfma_f32_16x16x32_bf16(aE[7], BB1, _a3, 0, 0, 0); \
    _Pragma("unroll") for (int _r = 0; _r < 4; ++_r) { \
      Y[_r]      = _a0[_r] * _w[_r]; \
      Y[4 + _r]  = _a1[_r] * _w[4 + _r]; \
      Y[8 + _r]  = _a2[_r] * _w[8 + _r]; \
      Y[12 + _r] = _a3[_r] * _w[12 + _r]; } \
    if ((T) == (CAP)) { LSNAP = (LINT); SNAPW(SNP, Y); } \
    if (RSC) { RESCALE(Y, LINT); } \
    BUILDBV(Y, BB0, BB1); }

    // zero snap slots (own-lane, no barrier needed)
#pragma unroll
    for (int k = 0; k < 4; ++k) { ((f4_t*)snp0)[k] = zro; ((f4_t*)snp1)[k] = zro; }

    // init from t=0
    LOADW(fA0, fA1, base0, 0); LOADW(gA0, gA1, base1, 0);
    {
      float w0x[16], w0z[16], ebT[16];
      CVT16(w0x, fA0, fA1); CVT16(w0z, gA0, gA1);
#pragma unroll
      for (int k = 0; k < 16; ++k)
        ebT[k] = __expf(beginT[(k >> 2) * 16 + q * 4 + (k & 3)]);
#pragma unroll
      for (int k = 0; k < 16; ++k) { y0[k] = w0x[k] * ebT[k]; y1[k] = w0z[k] * ebT[k]; }
      if (cap0 == 0) { Lsnap0 = 0; SNAPW(snp0, y0); }
      if (cap1 == 0) { Lsnap1 = 0; SNAPW(snp1, y1); }
    }
    RESCALE(y0, Lint0); RESCALE(y1, Lint1);
    BUILDBV(y0, xb0, xb1); BUILDBV(y1, zb0, zb1);
    LOADW(fA0, fA1, base0, 1); LOADW(gA0, gA1, base1, 1);
    LOADW(fB0, fB1, base0, 2); LOADW(gB0, gB1, base1, 2);
    LOADW(fC0, fC1, base0, 3); LOADW(gC0, gC1, base1, 3);
    LOADW(fD0, fD1, base0, 4); LOADW(gD0, gD1, base1, 4);

    for (int it = 0; it < 31; ++it) {
      const int t = 1 + 4 * it;
      STEPF(t + 0, y0, xb0, xb1, fA0, fA1, cap0, Lint0, Lsnap0, snp0, 0);
      STEPF(t + 0, y1, zb0, zb1, gA0, gA1, cap1, Lint1, Lsnap1, snp1, 0);
      LOADW(fA0, fA1, base0, t + 4); LOADW(gA0, gA1, base1, t + 4);
      STEPF(t + 1, y0, xb0, xb1, fB0, fB1, cap0, Lint0, Lsnap0, snp0, 0);
      STEPF(t + 1, y1, zb0, zb1, gB0, gB1, cap1, Lint1, Lsnap1, snp1, 0);
      LOADW(fB0, fB1, base0, t + 5); LOADW(gB0, gB1, base1, t + 5);
      STEPF(t + 2, y0, xb0, xb1, fC0, fC1, cap0, Lint0, Lsnap0, snp0, 1);
      STEPF(t + 2, y1, zb0, zb1, gC0, gC1, cap1, Lint1, Lsnap1, snp1, 1);
      LOADW(fC0, fC1, base0, t + 6); LOADW(gC0, gC1, base1, t + 6);
      STEPF(t + 3, y0, xb0, xb1, fD0, fD1, cap0, Lint0, Lsnap0, snp0, 0);
      STEPF(t + 3, y1, zb0, zb1, gD0, gD1, cap1, Lint1, Lsnap1, snp1, 0);
      LOADW(fD0, fD1, base0, t + 7); LOADW(gD0, gD1, base1, t + 7);
    }
    // tail: t = 125..127 (slots A=125, B=126, C=127 after last iter)
    STEPF(125, y0, xb0, xb1, fA0, fA1, cap0, Lint0, Lsnap0, snp0, 0);
    STEPF(125, y1, zb0, zb1, gA0, gA1, cap1, Lint1, Lsnap1, snp1, 0);
    STEPF(126, y0, xb0, xb1, fB0, fB1, cap0, Lint0, Lsnap0, snp0, 0);
    STEPF(126, y1, zb0, zb1, gB0, gB1, cap1, Lint1, Lsnap1, snp1, 0);
    STEPF(127, y0, xb0, xb1, fC0, fC1, cap0, Lint0, Lsnap0, snp0, 0);
    STEPF(127, y1, zb0, zb1, gC0, gC1, cap1, Lint1, Lsnap1, snp1, 0);

    // publish x_127 / scales / snap-dot
#pragma unroll
    for (int k = 0; k < 16; ++k) {
      xs[(0 * 64 + lane) * 16 + k] = y0[k];
      xs[(1 * 64 + lane) * 16 + k] = y1[k];
    }
    Lxs[0 * 64 + lane] = Lint0;
    Lxs[1 * 64 + lane] = Lint1;
    {
      float eend[16];
#pragma unroll
      for (int k = 0; k < 16; ++k)
        eend[k] = __expf(endT[(k >> 2) * 16 + q * 4 + (k & 3)]);
      float sd0 = 0.f, sd1 = 0.f;
#pragma unroll
      for (int k = 0; k < 16; ++k) { sd0 += snp0[k] * eend[k]; sd1 += snp1[k] * eend[k]; }
      sd0 += __shfl_xor(sd0, 16); sd0 += __shfl_xor(sd0, 32);
      sd1 += __shfl_xor(sd1, 16); sd1 += __shfl_xor(sd1, 32);
      if (lane < 16) {
        s0d[lane] = sd0;      Ls0[lane] = Lsnap0;
        s0d[16 + lane] = sd1; Ls0[16 + lane] = Lsnap1;
      }
    }

    // gold partial: t in [0,128), both chains
    for (int cc = 0; cc < 64; ++cc) {
      const int ch = cc >> 5;
      const int c  = cc & 31;
      const int tt = q + 4 * c;
      const int bb   = ch ? b1 : b0;
      const int lenc = ch ? len1 : len0;
      if (tt < lenc) {
        const int tg = tags[(size_t)tt * B_DIM + bb];
        float v = goldRaw[(size_t)tt * B_DIM + bb];
        v += (tt == 0) ? beginT[tg]
                       : trans[(size_t)tg * K_DIM + tags[(size_t)(tt - 1) * B_DIM + bb]];
        if (tt == lenc - 1) v += endT[tg];
        g0 += v;
      }
    }
    float gr = g0;
#pragma unroll
    for (int o = 1; o < 64; o <<= 1) gr += __shfl_xor(gr, o);
    if (lane == 0) gpart = gr;
  } else {
    // ---- backward wave: 2 interleaved chains ----
    bfrag_t aET[8];
#pragma unroll
    for (int jt = 0; jt < 4; ++jt)
#pragma unroll
      for (int kt = 0; kt < 2; ++kt) {
        union { bfrag_t v; __hip_bfloat16 h[8]; } u;
#pragma unroll
        for (int r = 0; r < 8; ++r) {
          const int i = (2 * kt + (r >> 2)) * 16 + q * 4 + (r & 3);
          u.h[r] = __float2bfloat16(__expf(trans[(size_t)i * K_DIM + (jt * 16 + n)]));
        }
        aET[jt * 2 + kt] = u.v;
      }

    float eend[16];
#pragma unroll
    for (int k = 0; k < 16; ++k)
      eend[k] = __expf(endT[(k >> 2) * 16 + q * 4 + (k & 3)]);

#define STEPB(T, Y, W0, W1, CAP, LINT, RSC) { \
    float _w[16]; \
    CVT16(_w, W0, W1); \
    const bool _hit = ((T) == (CAP)); \
    float _d[16]; \
    _Pragma("unroll") for (int _k = 0; _k < 16; ++_k) \
      _d[_k] = (_hit ? eend[_k] : Y[_k]) * _w[_k]; \
    bfrag_t _b0, _b1; \
    BUILDBV(_d, _b0, _b1); \
    f4_t _a0 = __builtin_amdgcn_mfma_f32_16x16x32_bf16(aET[0], _b0, zro, 0, 0, 0); \
    f4_t _a1 = __builtin_amdgcn_mfma_f32_16x16x32_bf16(aET[2], _b0, zro, 0, 0, 0); \
    f4_t _a2 = __builtin_amdgcn_mfma_f32_16x16x32_bf16(aET[4], _b0, zro, 0, 0, 0); \
    f4_t _a3 = __builtin_amdgcn_mfma_f32_16x16x32_bf16(aET[6], _b0, zro, 0, 0, 0); \
    _a0 = __builtin_amdgcn_mfma_f32_16x16x32_bf16(aET[1], _b1, _a0, 0, 0, 0); \
    _a1 = __builtin_amdgcn_mfma_f32_16x16x32_bf16(aET[3], _b1, _a1, 0, 0, 0); \
    _a2 = __builtin_amdgcn_mfma_f32_16x16x32_bf16(aET[5], _b1, _a2, 0, 0, 0); \
    _a3 = __builtin_amdgcn_mfma_f32_16x16x32_bf16(aET[7], _b1, _a3, 0, 0, 0); \
    _Pragma("unroll") for (int _r = 0; _r < 4; ++_r) { \
      Y[_r]      = _a0[_r]; \
      Y[4 + _r]  = _a1[_r]; \
      Y[8 + _r]  = _a2[_r]; \
      Y[12 + _r] = _a3[_r]; } \
    if (RSC) { RESCALE(Y, LINT); } }

#pragma unroll
    for (int k = 0; k < 16; ++k) { y0[k] = 0.f; y1[k] = 0.f; }
    LOADW(fA0, fA1, base0, 255); LOADW(gA0, gA1, base1, 255);
    LOADW(fB0, fB1, base0, 254); LOADW(gB0, gB1, base1, 254);
    LOADW(fC0, fC1, base0, 253); LOADW(gC0, gC1, base1, 253);
    LOADW(fD0, fD1, base0, 252); LOADW(gD0, gD1, base1, 252);

    for (int it = 0; it < 32; ++it) {
      const int t = 255 - 4 * it;
      STEPB(t - 0, y0, fA0, fA1, cap0, Lint0, 0);
      STEPB(t - 0, y1, gA0, gA1, cap1, Lint1, 0);
      LOADW(fA0, fA1, base0, t - 4); LOADW(gA0, gA1, base1, t - 4);
      STEPB(t - 1, y0, fB0, fB1, cap0, Lint0, 0);
      STEPB(t - 1, y1, gB0, gB1, cap1, Lint1, 0);
      LOADW(fB0, fB1, base0, t - 5); LOADW(gB0, gB1, base1, t - 5);
      STEPB(t - 2, y0, fC0, fC1, cap0, Lint0, 1);
      STEPB(t - 2, y1, gC0, gC1, cap1, Lint1, 1);
      LOADW(fC0, fC1, base0, t - 6); LOADW(gC0, gC1, base1, t - 6);
      STEPB(t - 3, y0, fD0, fD1, cap0, Lint0, 0);
      STEPB(t - 3, y1, gD0, gD1, cap1, Lint1, 0);
      LOADW(fD0, fD1, base0, t - 7); LOADW(gD0, gD1, base1, t - 7);
    }
    // y0/y1 = u_127 per chain (scales Lint0/Lint1)

    // gold partial: t in [128,256), both chains
    for (int cc = 0; cc < 64; ++cc) {
      const int ch = cc >> 5;
      const int c  = cc & 31;
      const int tt = 128 + q + 4 * c;
      const int bb   = ch ? b1 : b0;
      const int lenc = ch ? len1 : len0;
      if (tt < lenc) {
        const int tg = tags[(size_t)tt * B_DIM + bb];
        float v = goldRaw[(size_t)tt * B_DIM + bb];
        v += trans[(size_t)tg * K_DIM + tags[(size_t)(tt - 1) * B_DIM + bb]];
        if (tt == lenc - 1) v += endT[tg];
        g0 += v;
      }
    }
  }

  __syncthreads();

  if (wv == 1) {
    float d0 = 0.f, d1 = 0.f;
#pragma unroll
    for (int k = 0; k < 16; ++k) {
      d0 += xs[(0 * 64 + lane) * 16 + k] * y0[k];
      d1 += xs[(1 * 64 + lane) * 16 + k] * y1[k];
    }
    d0 += __shfl_xor(d0, 16); d0 += __shfl_xor(d0, 32);
    d1 += __shfl_xor(d1, 16); d1 += __shfl_xor(d1, 32);

    const bool hi0 = (cap0 >= 128), hi1 = (cap1 >= 128);
    const float ds0 = hi0 ? d0 : s0d[n];
    const float ds1 = hi1 ? d1 : s0d[16 + n];
    const float L0 = (float)(hi0 ? (Lxs[lane] + Lint0) : Ls0[n]);
    const float L1 = (float)(hi1 ? (Lxs[64 + lane] + Lint1) : Ls0[16 + n]);
    const float f = (__logf(ds0) + L0 * LN2F) + (__logf(ds1) + L1 * LN2F);

    float r = 0.25f * f - g0;
#pragma unroll
    for (int o = 1; o < 64; o <<= 1) r += __shfl_xor(r, o);
    if (lane == 0) atomicAdd(out, r - gpart);
  }
}

// ---------------------------------------------------------------------------
extern "C" void kernel_launch(void* const* d_in, const int* in_sizes, int n_in,
                              void* d_out, int out_size, void* d_ws, size_t ws_size,
                              hipStream_t stream) {
  const float* hiddens = (const float*)d_in[0];  // [T,B,H]
  const int*   lens    = (const int*)  d_in[1];  // [B]
  const int*   tags    = (const int*)  d_in[2];  // [T,B]
  const float* W       = (const float*)d_in[3];  // [K,H]
  const float* bias    = (const float*)d_in[4];  // [K]
  const float* beginT  = (const float*)d_in[5];  // [K]
  const float* trans   = (const float*)d_in[6];  // [K,K]
  const float* endT    = (const float*)d_in[7];  // [K]

  short* emPb    = (short*)d_ws;                            // 8.4 MB bf16
  float* goldRaw = (float*)(emPb + (size_t)16 * 256 * 64 * 16);  // 256 KB
  short* Wb      = (short*)(goldRaw + B_DIM * T_DIM);       // 64 KB bf16
  float* out     = (float*)d_out;

  wconv<<<(K_DIM * H_DIM) / (256 * 8), 256, 0, stream>>>(W, Wb, out);
  emis_gemm10<<<(T_DIM * B_DIM) / 64, 256, 0, stream>>>(hiddens, Wb, bias, tags, emPb, goldRaw);
  crf_dp11<<<8, 128, 0, stream>>>(emPb, goldRaw, lens, tags, trans, beginT, endT, out);
}

// Round 7
// 256.566 us; speedup vs baseline: 1.1079x; 1.1079x over previous
//
#include <hip/hip_runtime.h>
#include <hip/hip_bf16.h>
#include <math.h>

#define T_DIM 256
#define B_DIM 256
#define H_DIM 512
#define K_DIM 64
#define LN2F 0.69314718055994531f

typedef __attribute__((ext_vector_type(8))) short bfrag_t;  // 8 bf16 (4 VGPRs)
typedef __attribute__((ext_vector_type(4))) float f4_t;     // 4 fp32

// Pack 8 fp32 -> 8 bf16 (RNE) for an MFMA A/B fragment.
__device__ inline bfrag_t pack8(float4 a, float4 b) {
  union { bfrag_t v; __hip_bfloat162 h[4]; } u;
  u.h[0] = __float22bfloat162_rn(float2{a.x, a.y});
  u.h[1] = __float22bfloat162_rn(float2{a.z, a.w});
  u.h[2] = __float22bfloat162_rn(float2{b.x, b.y});
  u.h[3] = __float22bfloat162_rn(float2{b.z, b.w});
  return u.v;
}

// ---------------------------------------------------------------------------
// W pre-convert + out zeroing (unchanged, verified).
// ---------------------------------------------------------------------------
__global__ __launch_bounds__(256) void wconv(const float* __restrict__ W,
                                             short* __restrict__ Wb,
                                             float* __restrict__ out) {
  if (blockIdx.x == 0 && threadIdx.x == 0) *out = 0.f;
  const int i = (blockIdx.x * 256 + threadIdx.x) * 8;
  const float4 a = *(const float4*)(W + i);
  const float4 b = *(const float4*)(W + i + 4);
  *(bfrag_t*)(Wb + i) = pack8(a, b);
}

// ---------------------------------------------------------------------------
// Emission GEMM v10 (unchanged, verified): 64x64 tile, BK=64, 1-deep A
// prefetch, LDS pad-8 bf16 A-staging, streamed L2 B-frags, 4 blocks/CU,
// raw-score epilogue + fp32 gold gather, bf16 emP output.
// ---------------------------------------------------------------------------
__global__ __launch_bounds__(256, 4) void emis_gemm10(
    const float* __restrict__ hid,   // [T*B, H]
    const short* __restrict__ Wb,    // [K,H] bf16
    const float* __restrict__ bias,  // [K]
    const int*   __restrict__ tags,  // [T,B]
    short* __restrict__ emPb,        // [16,256,64,16] bf16 (permuted exp scores)
    float* __restrict__ goldRaw)     // [T,B] raw score at gold tag (fp32)
{
  __shared__ __hip_bfloat16 AsH[2][64 * 72];     // 2 x 9216 B
  float* Cs = (float*)&AsH[0][0];                // epilogue reuse

  const int tid  = threadIdx.x;
  const int wv   = tid >> 6;
  const int lane = tid & 63;
  const int l16  = lane & 15;
  const int quad = lane >> 4;
  const int m0   = blockIdx.x * 64;

  const short* wb = Wb + ((wv * 16 + l16) * H_DIM + quad * 8);

  const int sr = tid >> 2;
  const int sc = (tid & 3) << 4;
  const float* hrow = hid + (size_t)(m0 + sr) * H_DIM + sc;

  f4_t acc[4];
#pragma unroll
  for (int mt = 0; mt < 4; ++mt) acc[mt] = (f4_t){0.f, 0.f, 0.f, 0.f};

  float4 p0 = *(const float4*)(hrow + 0);
  float4 p1 = *(const float4*)(hrow + 4);
  float4 p2 = *(const float4*)(hrow + 8);
  float4 p3 = *(const float4*)(hrow + 12);
  bfrag_t bc0 = *(const bfrag_t*)(wb + 0);
  bfrag_t bc1 = *(const bfrag_t*)(wb + 32);
  *(bfrag_t*)(&AsH[0][sr * 72 + sc + 0]) = pack8(p0, p1);
  *(bfrag_t*)(&AsH[0][sr * 72 + sc + 8]) = pack8(p2, p3);
  __syncthreads();

#pragma unroll
  for (int it = 0; it < 8; ++it) {
    bfrag_t bn0, bn1;
    if (it < 7) {
      p0 = *(const float4*)(hrow + (it + 1) * 64 + 0);
      p1 = *(const float4*)(hrow + (it + 1) * 64 + 4);
      p2 = *(const float4*)(hrow + (it + 1) * 64 + 8);
      p3 = *(const float4*)(hrow + (it + 1) * 64 + 12);
      bn0 = *(const bfrag_t*)(wb + (it + 1) * 64);
      bn1 = *(const bfrag_t*)(wb + (it + 1) * 64 + 32);
    }
#pragma unroll
    for (int kc2 = 0; kc2 < 2; ++kc2) {
      const bfrag_t bf = kc2 ? bc1 : bc0;
#pragma unroll
      for (int mt = 0; mt < 4; ++mt) {
        const bfrag_t af =
            *(const bfrag_t*)(&AsH[it & 1][(mt * 16 + l16) * 72 + kc2 * 32 + quad * 8]);
        acc[mt] = __builtin_amdgcn_mfma_f32_16x16x32_bf16(af, bf, acc[mt], 0, 0, 0);
      }
    }
    if (it < 7) {
      *(bfrag_t*)(&AsH[(it + 1) & 1][sr * 72 + sc + 0]) = pack8(p0, p1);
      *(bfrag_t*)(&AsH[(it + 1) & 1][sr * 72 + sc + 8]) = pack8(p2, p3);
      bc0 = bn0; bc1 = bn1;
    }
    __syncthreads();
  }

  const float bn = bias[wv * 16 + l16];
#pragma unroll
  for (int mt = 0; mt < 4; ++mt)
#pragma unroll
    for (int r = 0; r < 4; ++r)
      Cs[(mt * 16 + quad * 4 + r) * 68 + wv * 16 + l16] = acc[mt][r] + bn;
  __syncthreads();

  const int t  = m0 >> 8;
  const int b0 = m0 & 255;
  if (tid < 64) {
    const int tg = tags[t * B_DIM + b0 + tid];
    goldRaw[t * B_DIM + b0 + tid] = Cs[tid * 68 + tg];
  }

  const int g0 = b0 >> 4;
  const int bl = tid & 15;
  const int qq = (tid >> 4) & 3;
  const int gl = tid >> 6;
#pragma unroll
  for (int i2 = 0; i2 < 2; ++i2) {
    float4 v0 = *(const float4*)(&Cs[(gl * 16 + bl) * 68 + (i2 * 2 + 0) * 16 + qq * 4]);
    float4 v1 = *(const float4*)(&Cs[(gl * 16 + bl) * 68 + (i2 * 2 + 1) * 16 + qq * 4]);
    v0.x = __expf(v0.x); v0.y = __expf(v0.y); v0.z = __expf(v0.z); v0.w = __expf(v0.w);
    v1.x = __expf(v1.x); v1.y = __expf(v1.y); v1.z = __expf(v1.z); v1.w = __expf(v1.w);
    const size_t off = ((((size_t)(g0 + gl) * 256 + t) * 64 + qq * 16 + bl) << 4) + i2 * 8;
    *(bfrag_t*)(emPb + off) = pack8(v0, v1);
  }
}

// ---------------------------------------------------------------------------
// CRF DP v12 = v10 (16 blocks, 2 waves, 8-deep bf16 ring, cvt-at-use) +
// sched_barrier(0) WALLS around every LOADW. R6 diagnosis: the compiler
// SINKS the ring loads to their use sites (VGPR 132 vs ~190 live, no spill
// traffic, ~90% stall) -> every step eats full L2/HBM latency. The walls pin
// the 8-step prefetch distance; the waitcnt pass then emits counted vmcnt
// (oldest-2-of-16) instead of a full-latency wait.
// ---------------------------------------------------------------------------
#define SBAR() __builtin_amdgcn_sched_barrier(0)

__global__ __launch_bounds__(128, 1) void crf_dp12(
    const short* __restrict__ emPb,
    const float* __restrict__ goldRaw,
    const int* __restrict__ lens,
    const int* __restrict__ tags,
    const float* __restrict__ trans,
    const float* __restrict__ beginT,
    const float* __restrict__ endT,
    float* __restrict__ out)
{
  const int g    = blockIdx.x;
  const int tid  = threadIdx.x;
  const int wv   = tid >> 6;     // 0 = forward, 1 = backward
  const int lane = tid & 63;
  const int n    = lane & 15;
  const int q    = lane >> 4;
  const int b    = g * 16 + n;

  __shared__ float xs[64 * 16];  // x_127 per fwd-lane
  __shared__ int   Lxs[64];
  __shared__ float s0d[16];      // snap·eend per column
  __shared__ int   Ls0[16];
  __shared__ float gpart;        // wave0 gold partial

  const int len = lens[b];
  const int cap = len - 1;
  const short* base = emPb + (((size_t)g * 256) * 64 + lane) * 16;

  float eend[16];
#pragma unroll
  for (int k = 0; k < 16; ++k)
    eend[k] = __expf(endT[(k >> 2) * 16 + q * 4 + (k & 3)]);

  float y[16];
  int Lint = 0;
  bfrag_t bf0, bf1;
  // bf16 prefetch ring: 8 slots x 2 bfrag_t = 64 VGPR
  bfrag_t wA0, wA1, wB0, wB1, wC0, wC1, wD0, wD1;
  bfrag_t wE0, wE1, wF0, wF1, wG0, wG1, wH0, wH1;
  float g0 = 0.f;

#define LOADW(D0, D1, t) { \
    D0 = *(const bfrag_t*)(base + (size_t)(t) * 1024 + 0); \
    D1 = *(const bfrag_t*)(base + (size_t)(t) * 1024 + 8); }

#define CVT16(DST, S0, S1) { \
    union { bfrag_t v; __hip_bfloat162 h[4]; } _c0, _c1; \
    _c0.v = (S0); _c1.v = (S1); \
    float2 _f; \
    _f = __bfloat1622float2(_c0.h[0]); DST[0] = _f.x; DST[1] = _f.y; \
    _f = __bfloat1622float2(_c0.h[1]); DST[2] = _f.x; DST[3] = _f.y; \
    _f = __bfloat1622float2(_c0.h[2]); DST[4] = _f.x; DST[5] = _f.y; \
    _f = __bfloat1622float2(_c0.h[3]); DST[6] = _f.x; DST[7] = _f.y; \
    _f = __bfloat1622float2(_c1.h[0]); DST[8] = _f.x; DST[9] = _f.y; \
    _f = __bfloat1622float2(_c1.h[1]); DST[10] = _f.x; DST[11] = _f.y; \
    _f = __bfloat1622float2(_c1.h[2]); DST[12] = _f.x; DST[13] = _f.y; \
    _f = __bfloat1622float2(_c1.h[3]); DST[14] = _f.x; DST[15] = _f.y; }

#define RESCALE() { \
    float _m0 = fmaxf(fmaxf(y[0], y[1]), fmaxf(y[2], y[3])); \
    float _m1 = fmaxf(fmaxf(y[4], y[5]), fmaxf(y[6], y[7])); \
    float _m2 = fmaxf(fmaxf(y[8], y[9]), fmaxf(y[10], y[11])); \
    float _m3 = fmaxf(fmaxf(y[12], y[13]), fmaxf(y[14], y[15])); \
    float _mx = fmaxf(fmaxf(_m0, _m1), fmaxf(_m2, _m3)); \
    _mx = fmaxf(_mx, __shfl_xor(_mx, 16)); \
    _mx = fmaxf(_mx, __shfl_xor(_mx, 32)); \
    int _e; (void)frexpf(_mx, &_e); \
    Lint += _e; \
    _Pragma("unroll") for (int k = 0; k < 16; ++k) y[k] = ldexpf(y[k], -_e); }

#define BUILDBV(S) { \
    union { bfrag_t v; __hip_bfloat162 h[4]; } _u0, _u1; \
    _u0.h[0] = __float22bfloat162_rn(float2{S[0], S[1]}); \
    _u0.h[1] = __float22bfloat162_rn(float2{S[2], S[3]}); \
    _u0.h[2] = __float22bfloat162_rn(float2{S[4], S[5]}); \
    _u0.h[3] = __float22bfloat162_rn(float2{S[6], S[7]}); \
    _u1.h[0] = __float22bfloat162_rn(float2{S[8], S[9]}); \
    _u1.h[1] = __float22bfloat162_rn(float2{S[10], S[11]}); \
    _u1.h[2] = __float22bfloat162_rn(float2{S[12], S[13]}); \
    _u1.h[3] = __float22bfloat162_rn(float2{S[14], S[15]}); \
    bf0 = _u0.v; bf1 = _u1.v; }

  const f4_t zro = (f4_t){0.f, 0.f, 0.f, 0.f};

  if (wv == 0) {
    // ---- forward wave ----
    bfrag_t aE[8];
#pragma unroll
    for (int jt = 0; jt < 4; ++jt)
#pragma unroll
      for (int kt = 0; kt < 2; ++kt) {
        union { bfrag_t v; __hip_bfloat16 h[8]; } u;
#pragma unroll
        for (int r = 0; r < 8; ++r) {
          const int i = (2 * kt + (r >> 2)) * 16 + q * 4 + (r & 3);
          u.h[r] = __float2bfloat16(__expf(trans[(jt * 16 + n) * K_DIM + i]));
        }
        aE[jt * 2 + kt] = u.v;
      }

    float snap[16];
    int Lsnap = 0;
    LOADW(wA0, wA1, 0);
    {
      float w0[16];
      CVT16(w0, wA0, wA1);
#pragma unroll
      for (int k = 0; k < 16; ++k) {
        const int j = (k >> 2) * 16 + q * 4 + (k & 3);
        y[k] = w0[k] * __expf(beginT[j]);
        snap[k] = (cap == 0) ? y[k] : 0.0f;
      }
    }
    RESCALE(); BUILDBV(y);
    LOADW(wA0, wA1, 1); LOADW(wB0, wB1, 2); LOADW(wC0, wC1, 3); LOADW(wD0, wD1, 4);
    LOADW(wE0, wE1, 5); LOADW(wF0, wF1, 6); LOADW(wG0, wG1, 7); LOADW(wH0, wH1, 8);
    SBAR();

#define STEPF(T, W0, W1, RSC) { \
    float _w[16]; \
    CVT16(_w, W0, W1); \
    f4_t _a0 = __builtin_amdgcn_mfma_f32_16x16x32_bf16(aE[0], bf0, zro, 0, 0, 0); \
    f4_t _a1 = __builtin_amdgcn_mfma_f32_16x16x32_bf16(aE[2], bf0, zro, 0, 0, 0); \
    f4_t _a2 = __builtin_amdgcn_mfma_f32_16x16x32_bf16(aE[4], bf0, zro, 0, 0, 0); \
    f4_t _a3 = __builtin_amdgcn_mfma_f32_16x16x32_bf16(aE[6], bf0, zro, 0, 0, 0); \
    _a0 = __builtin_amdgcn_mfma_f32_16x16x32_bf16(aE[1], bf1, _a0, 0, 0, 0); \
    _a1 = __builtin_amdgcn_mfma_f32_16x16x32_bf16(aE[3], bf1, _a1, 0, 0, 0); \
    _a2 = __builtin_amdgcn_mfma_f32_16x16x32_bf16(aE[5], bf1, _a2, 0, 0, 0); \
    _a3 = __builtin_amdgcn_mfma_f32_16x16x32_bf16(aE[7], bf1, _a3, 0, 0, 0); \
    _Pragma("unroll") for (int r = 0; r < 4; ++r) { \
      y[r]      = _a0[r] * _w[r]; \
      y[4 + r]  = _a1[r] * _w[4 + r]; \
      y[8 + r]  = _a2[r] * _w[8 + r]; \
      y[12 + r] = _a3[r] * _w[12 + r]; } \
    const bool _hit = ((T) == cap); \
    _Pragma("unroll") for (int k = 0; k < 16; ++k) snap[k] = _hit ? y[k] : snap[k]; \
    Lsnap = _hit ? Lint : Lsnap; \
    if (RSC) { RESCALE(); } \
    BUILDBV(y); }

    int t = 1;
    for (int it = 0; it < 15; ++it, t += 8) {
      STEPF(t + 0, wA0, wA1, 0); SBAR(); LOADW(wA0, wA1, t + 8);  SBAR();
      STEPF(t + 1, wB0, wB1, 0); SBAR(); LOADW(wB0, wB1, t + 9);  SBAR();
      STEPF(t + 2, wC0, wC1, 1); SBAR(); LOADW(wC0, wC1, t + 10); SBAR();
      STEPF(t + 3, wD0, wD1, 0); SBAR(); LOADW(wD0, wD1, t + 11); SBAR();
      STEPF(t + 4, wE0, wE1, 0); SBAR(); LOADW(wE0, wE1, t + 12); SBAR();
      STEPF(t + 5, wF0, wF1, 0); SBAR(); LOADW(wF0, wF1, t + 13); SBAR();
      STEPF(t + 6, wG0, wG1, 1); SBAR(); LOADW(wG0, wG1, t + 14); SBAR();
      STEPF(t + 7, wH0, wH1, 0); SBAR(); LOADW(wH0, wH1, t + 15); SBAR();
    }
    // tail: t = 121..127
    STEPF(121, wA0, wA1, 0); STEPF(122, wB0, wB1, 0); STEPF(123, wC0, wC1, 1);
    STEPF(124, wD0, wD1, 0); STEPF(125, wE0, wE1, 0); STEPF(126, wF0, wF1, 0);
    STEPF(127, wG0, wG1, 0);

    // publish x_127 / scales / snap-dot
#pragma unroll
    for (int k = 0; k < 16; ++k) xs[lane * 16 + k] = y[k];
    Lxs[lane] = Lint;
    float sd = 0.f;
#pragma unroll
    for (int k = 0; k < 16; ++k) sd += snap[k] * eend[k];
    sd += __shfl_xor(sd, 16);
    sd += __shfl_xor(sd, 32);
    if (lane < 16) { s0d[lane] = sd; Ls0[lane] = Lsnap; }

    // gold partial: t in [0,128)
    for (int c = 0; c < 32; ++c) {
      const int tt = q + 4 * c;
      if (tt < len) {
        const int tg = tags[(size_t)tt * B_DIM + b];
        float v = goldRaw[(size_t)tt * B_DIM + b];
        v += (tt == 0) ? beginT[tg]
                       : trans[(size_t)tg * K_DIM + tags[(size_t)(tt - 1) * B_DIM + b]];
        if (tt == cap) v += endT[tg];
        g0 += v;
      }
    }
    float gr = g0;
#pragma unroll
    for (int o = 1; o < 64; o <<= 1) gr += __shfl_xor(gr, o);
    if (lane == 0) gpart = gr;
  } else {
    // ---- backward wave ----
    bfrag_t aET[8];
#pragma unroll
    for (int jt = 0; jt < 4; ++jt)
#pragma unroll
      for (int kt = 0; kt < 2; ++kt) {
        union { bfrag_t v; __hip_bfloat16 h[8]; } u;
#pragma unroll
        for (int r = 0; r < 8; ++r) {
          const int i = (2 * kt + (r >> 2)) * 16 + q * 4 + (r & 3);
          u.h[r] = __float2bfloat16(__expf(trans[(size_t)i * K_DIM + (jt * 16 + n)]));
        }
        aET[jt * 2 + kt] = u.v;
      }

#pragma unroll
    for (int k = 0; k < 16; ++k) y[k] = 0.f;
    LOADW(wA0, wA1, 255); LOADW(wB0, wB1, 254); LOADW(wC0, wC1, 253); LOADW(wD0, wD1, 252);
    LOADW(wE0, wE1, 251); LOADW(wF0, wF1, 250); LOADW(wG0, wG1, 249); LOADW(wH0, wH1, 248);
    SBAR();

#define STEPB(T, W0, W1, RSC) { \
    float _w[16]; \
    CVT16(_w, W0, W1); \
    const bool _hit = ((T) == cap); \
    float _d[16]; \
    _Pragma("unroll") for (int k = 0; k < 16; ++k) \
      _d[k] = (_hit ? eend[k] : y[k]) * _w[k]; \
    BUILDBV(_d); \
    f4_t _a0 = __builtin_amdgcn_mfma_f32_16x16x32_bf16(aET[0], bf0, zro, 0, 0, 0); \
    f4_t _a1 = __builtin_amdgcn_mfma_f32_16x16x32_bf16(aET[2], bf0, zro, 0, 0, 0); \
    f4_t _a2 = __builtin_amdgcn_mfma_f32_16x16x32_bf16(aET[4], bf0, zro, 0, 0, 0); \
    f4_t _a3 = __builtin_amdgcn_mfma_f32_16x16x32_bf16(aET[6], bf0, zro, 0, 0, 0); \
    _a0 = __builtin_amdgcn_mfma_f32_16x16x32_bf16(aET[1], bf1, _a0, 0, 0, 0); \
    _a1 = __builtin_amdgcn_mfma_f32_16x16x32_bf16(aET[3], bf1, _a1, 0, 0, 0); \
    _a2 = __builtin_amdgcn_mfma_f32_16x16x32_bf16(aET[5], bf1, _a2, 0, 0, 0); \
    _a3 = __builtin_amdgcn_mfma_f32_16x16x32_bf16(aET[7], bf1, _a3, 0, 0, 0); \
    _Pragma("unroll") for (int r = 0; r < 4; ++r) { \
      y[r]      = _a0[r]; \
      y[4 + r]  = _a1[r]; \
      y[8 + r]  = _a2[r]; \
      y[12 + r] = _a3[r]; } \
    if (RSC) { RESCALE(); } }

    int t = 255;
    for (int it = 0; it < 16; ++it, t -= 8) {
      STEPB(t - 0, wA0, wA1, 0); SBAR(); LOADW(wA0, wA1, t - 8);  SBAR();
      STEPB(t - 1, wB0, wB1, 0); SBAR(); LOADW(wB0, wB1, t - 9);  SBAR();
      STEPB(t - 2, wC0, wC1, 1); SBAR(); LOADW(wC0, wC1, t - 10); SBAR();
      STEPB(t - 3, wD0, wD1, 0); SBAR(); LOADW(wD0, wD1, t - 11); SBAR();
      STEPB(t - 4, wE0, wE1, 0); SBAR(); LOADW(wE0, wE1, t - 12); SBAR();
      STEPB(t - 5, wF0, wF1, 0); SBAR(); LOADW(wF0, wF1, t - 13); SBAR();
      STEPB(t - 6, wG0, wG1, 1); SBAR(); LOADW(wG0, wG1, t - 14); SBAR();
      STEPB(t - 7, wH0, wH1, 0); SBAR(); LOADW(wH0, wH1, t - 15); SBAR();
    }
    // y = u_127 (scale Lint = Lu)

    // gold partial: t in [128,256)
    for (int c = 0; c < 32; ++c) {
      const int tt = 128 + q + 4 * c;
      if (tt < len) {
        const int tg = tags[(size_t)tt * B_DIM + b];
        float v = goldRaw[(size_t)tt * B_DIM + b];
        v += trans[(size_t)tg * K_DIM + tags[(size_t)(tt - 1) * B_DIM + b]];
        if (tt == cap) v += endT[tg];
        g0 += v;
      }
    }
  }

  __syncthreads();

  if (wv == 1) {
    float dot1 = 0.f;
#pragma unroll
    for (int k = 0; k < 16; ++k) dot1 += xs[lane * 16 + k] * y[k];
    dot1 += __shfl_xor(dot1, 16);
    dot1 += __shfl_xor(dot1, 32);

    const bool hi = (cap >= 128);
    const float dsel = hi ? dot1 : s0d[n];
    const float Lsel = (float)(hi ? (Lxs[lane] + Lint) : Ls0[n]);
    const float f = __logf(dsel) + Lsel * LN2F;

    float r = 0.25f * f - g0;
#pragma unroll
    for (int o = 1; o < 64; o <<= 1) r += __shfl_xor(r, o);
    if (lane == 0) atomicAdd(out, r - gpart);
  }
}

// ---------------------------------------------------------------------------
extern "C" void kernel_launch(void* const* d_in, const int* in_sizes, int n_in,
                              void* d_out, int out_size, void* d_ws, size_t ws_size,
                              hipStream_t stream) {
  const float* hiddens = (const float*)d_in[0];  // [T,B,H]
  const int*   lens    = (const int*)  d_in[1];  // [B]
  const int*   tags    = (const int*)  d_in[2];  // [T,B]
  const float* W       = (const float*)d_in[3];  // [K,H]
  const float* bias    = (const float*)d_in[4];  // [K]
  const float* beginT  = (const float*)d_in[5];  // [K]
  const float* trans   = (const float*)d_in[6];  // [K,K]
  const float* endT    = (const float*)d_in[7];  // [K]

  short* emPb    = (short*)d_ws;                            // 8.4 MB bf16
  float* goldRaw = (float*)(emPb + (size_t)16 * 256 * 64 * 16);  // 256 KB
  short* Wb      = (short*)(goldRaw + B_DIM * T_DIM);       // 64 KB bf16
  float* out     = (float*)d_out;

  wconv<<<(K_DIM * H_DIM) / (256 * 8), 256, 0, stream>>>(W, Wb, out);
  emis_gemm10<<<(T_DIM * B_DIM) / 64, 256, 0, stream>>>(hiddens, Wb, bias, tags, emPb, goldRaw);
  crf_dp12<<<16, 128, 0, stream>>>(emPb, goldRaw, lens, tags, trans, beginT, endT, out);
}